// Round 1
// baseline (527.969 us; speedup 1.0000x reference)
//
#include <hip/hip_runtime.h>

#define Bdim 256
#define Cdim 128
#define Hdim 1024
#define Idim 512
#define Odim 128

#define BT 64     // batch tile rows per block
#define HT 128    // hidden tile
#define BK 64     // K tile for layer 1

// padded LDS leading dims (keep 16B alignment: LD*2 % 16 == 0, LD%32 != 0 banks)
#define XS_LD  72
#define W1S_LD 72
#define W2S_LD 136
#define HS_LD  136

typedef __attribute__((ext_vector_type(8))) short short8;
typedef __attribute__((ext_vector_type(4))) float f32x4;

__global__ __launch_bounds__(256, 2) void mlp_fused(
    const float* __restrict__ x, const float* __restrict__ w1,
    const float* __restrict__ b1, const float* __restrict__ w2,
    const float* __restrict__ b2, float* __restrict__ out)
{
    __shared__ unsigned char smem[52224];
    unsigned short* Xs  = (unsigned short*)smem;            // [64][72]   9216 B
    unsigned short* W1s = (unsigned short*)(smem + 9216);   // [128][72]  18432 B
    unsigned short* W2s = (unsigned short*)smem;            // [128][136] 34816 B (aliases Xs+W1s)
    unsigned short* Hs  = (unsigned short*)(smem + 34816);  // [64][136]  17408 B

    const int t    = threadIdx.x;
    const int lane = t & 63;
    const int q    = lane >> 4;   // quad 0..3
    const int r16  = lane & 15;
    const int wave = t >> 6;
    const int wm   = wave >> 1;   // 0..1 -> m0 = wm*32
    const int wn   = wave & 1;    // 0..1 -> n0 = wn*64

    // XCD-aware swizzle: blocks for channels g*16..g*16+15 land on XCD g
    // so out[b,o,c] 64B lines (16 consecutive c) are assembled in one L2.
    const int bid = blockIdx.x;
    const int g   = bid & 7;
    const int s   = bid >> 3;          // 0..63
    const int c   = g * 16 + (s & 15); // channel
    const int bt  = s >> 4;            // 0..3
    const int row0 = bt * BT;

    // staging thread decomposition
    const int tx    = t & 15;   // 16 thr * float4 = 64 cols (Xs/W1s)
    const int trow  = t >> 4;   // 16 rows per pass
    const int tx32  = t & 31;   // 32 thr * float4 = 128 cols (W2s)
    const int trow8 = t >> 5;   // 8 rows per pass

    const float* xbase  = x  + ((size_t)row0 * Cdim + c) * Idim;
    const float* w1base = w1 + (size_t)c * Hdim * Idim;
    const float* w2base = w2 + (size_t)c * Odim * Hdim;

    // persistent layer-2 accumulators, init with b2 broadcast (n depends on j only)
    f32x4 acc2[2][4];
    for (int j = 0; j < 4; ++j) {
        float bv = b2[c * Odim + wn * 64 + j * 16 + r16];
        f32x4 z = {bv, bv, bv, bv};
        acc2[0][j] = z;
        acc2[1][j] = z;
    }

    for (int ht = 0; ht < Hdim / HT; ++ht) {
        f32x4 acc1[2][4];
        {
            f32x4 z = {0.f, 0.f, 0.f, 0.f};
            for (int i = 0; i < 2; ++i)
                for (int j = 0; j < 4; ++j) acc1[i][j] = z;
        }

        for (int kt = 0; kt < Idim / BK; ++kt) {
            __syncthreads();   // protect LDS region A from previous consumers
            // stage W1s (128x64) and Xs (64x64), fp32 -> bf16 (truncate via v_perm)
            #pragma unroll
            for (int p = 0; p < 8; ++p) {
                int rr = trow + p * 16;
                float4 v = *(const float4*)(w1base + (size_t)(ht * HT + rr) * Idim + kt * BK + tx * 4);
                unsigned int lo = __builtin_amdgcn_perm(__float_as_uint(v.y), __float_as_uint(v.x), 0x07060302);
                unsigned int hi = __builtin_amdgcn_perm(__float_as_uint(v.w), __float_as_uint(v.z), 0x07060302);
                *(uint2*)&W1s[rr * W1S_LD + tx * 4] = make_uint2(lo, hi);
                if (p < 4) {
                    float4 xv = *(const float4*)(xbase + (size_t)rr * (Cdim * Idim) + kt * BK + tx * 4);
                    unsigned int xlo = __builtin_amdgcn_perm(__float_as_uint(xv.y), __float_as_uint(xv.x), 0x07060302);
                    unsigned int xhi = __builtin_amdgcn_perm(__float_as_uint(xv.w), __float_as_uint(xv.z), 0x07060302);
                    *(uint2*)&Xs[rr * XS_LD + tx * 4] = make_uint2(xlo, xhi);
                }
            }
            __syncthreads();
            #pragma unroll
            for (int ks = 0; ks < 2; ++ks) {
                int k0 = ks * 32 + q * 8;
                short8 a[2], b[4];
                #pragma unroll
                for (int i = 0; i < 2; ++i)
                    a[i] = *(const short8*)&Xs[(wm * 32 + i * 16 + r16) * XS_LD + k0];
                #pragma unroll
                for (int j = 0; j < 4; ++j)
                    b[j] = *(const short8*)&W1s[(wn * 64 + j * 16 + r16) * W1S_LD + k0];
                #pragma unroll
                for (int i = 0; i < 2; ++i)
                    #pragma unroll
                    for (int j = 0; j < 4; ++j)
                        acc1[i][j] = __builtin_amdgcn_mfma_f32_16x16x32_bf16(a[i], b[j], acc1[i][j], 0, 0, 0);
            }
        }
        __syncthreads();   // all waves done reading Xs/W1s; prev-ht Hs fully consumed

        // stage W2s (128 o x 128 h) into region A
        #pragma unroll
        for (int p = 0; p < 16; ++p) {
            int rr = trow8 + p * 8;
            float4 v = *(const float4*)(w2base + (size_t)rr * Hdim + ht * HT + tx32 * 4);
            unsigned int lo = __builtin_amdgcn_perm(__float_as_uint(v.y), __float_as_uint(v.x), 0x07060302);
            unsigned int hi = __builtin_amdgcn_perm(__float_as_uint(v.w), __float_as_uint(v.z), 0x07060302);
            *(uint2*)&W2s[rr * W2S_LD + tx32 * 4] = make_uint2(lo, hi);
        }
        // epilogue layer 1: Hs = bf16(relu(acc1 + b1))
        for (int j = 0; j < 4; ++j) {
            int n = wn * 64 + j * 16 + r16;
            float b1v = b1[c * Hdim + ht * HT + n];
            #pragma unroll
            for (int i = 0; i < 2; ++i) {
                #pragma unroll
                for (int r = 0; r < 4; ++r) {
                    int m = wm * 32 + i * 16 + q * 4 + r;
                    float hv = fmaxf(acc1[i][j][r] + b1v, 0.f);
                    Hs[m * HS_LD + n] = (unsigned short)(__float_as_uint(hv) >> 16);
                }
            }
        }
        __syncthreads();
        // layer 2 partial: acc2 += Hs (64x128) * W2s^T (128h x 128o)
        #pragma unroll
        for (int ks = 0; ks < 4; ++ks) {
            int k0 = ks * 32 + q * 8;
            short8 a[2], b[4];
            #pragma unroll
            for (int i = 0; i < 2; ++i)
                a[i] = *(const short8*)&Hs[(wm * 32 + i * 16 + r16) * HS_LD + k0];
            #pragma unroll
            for (int j = 0; j < 4; ++j)
                b[j] = *(const short8*)&W2s[(wn * 64 + j * 16 + r16) * W2S_LD + k0];
            #pragma unroll
            for (int i = 0; i < 2; ++i)
                #pragma unroll
                for (int j = 0; j < 4; ++j)
                    acc2[i][j] = __builtin_amdgcn_mfma_f32_16x16x32_bf16(a[i], b[j], acc2[i][j], 0, 0, 0);
        }
    }

    // store: out[b, o, c] = b*O*C + o*C + c   (scattered dwords; XCD swizzle
    // groups the 16 c-writers of each 64B line onto one XCD for L2 merging)
    #pragma unroll
    for (int i = 0; i < 2; ++i)
        #pragma unroll
        for (int j = 0; j < 4; ++j)
            #pragma unroll
            for (int r = 0; r < 4; ++r) {
                int bb = row0 + wm * 32 + i * 16 + q * 4 + r;
                int o  = wn * 64 + j * 16 + r16;
                out[(size_t)bb * (Odim * Cdim) + o * Cdim + c] = acc2[i][j][r];
            }
}

extern "C" void kernel_launch(void* const* d_in, const int* in_sizes, int n_in,
                              void* d_out, int out_size, void* d_ws, size_t ws_size,
                              hipStream_t stream) {
    const float* x  = (const float*)d_in[0];
    const float* w1 = (const float*)d_in[1];
    const float* b1 = (const float*)d_in[2];
    const float* w2 = (const float*)d_in[3];
    const float* b2 = (const float*)d_in[4];
    float* out = (float*)d_out;
    mlp_fused<<<dim3(512), dim3(256), 0, stream>>>(x, w1, b1, w2, b2, out);
}